// Round 8
// baseline (31.318 us; speedup 1.0000x reference)
//
#include <hip/hip_runtime.h>
#include <math.h>

#define B 1000
#define D 8
#define PRE 98
#define NEXT 512
#define SC 32
#define ANT 5
#define BM 32
#define NTILE 32          // 1000/32 -> 32 tiles (last partial)
#define KP 128            // PRE padded to 128 for MFMA K-steps

using bf16x8 = __attribute__((ext_vector_type(8))) short;
using f32x4  = __attribute__((ext_vector_type(4))) float;

static __device__ __forceinline__ unsigned short f2bf(float f) {
    union { float f; unsigned u; } v{f};
    unsigned r = (v.u + 0x7fffu + ((v.u >> 16) & 1u)) >> 16;
    return (unsigned short)r;
}
static __device__ __forceinline__ float bf2f(unsigned short h) {
    union { unsigned u; float f; } v{(unsigned)h << 16};
    return v.f;
}

// ---------------------------------------------------------------------------
// Prep: transpose/convert weights to bf16:
//   sub_wT[d][n][k] (k padded to 128 with 0) = sub_w[d][k][n]
//   cut_wT[d][c][k]                          = cut_w[d][k][c]
// ---------------------------------------------------------------------------
__global__ __launch_bounds__(256) void k_prep(const float* __restrict__ sub_w,
                                              const float* __restrict__ cut_w,
                                              unsigned short* __restrict__ sub_wT,
                                              unsigned short* __restrict__ cut_wT) {
    __shared__ __align__(16) unsigned short tile[32][128];
    int t = threadIdx.x, bid = blockIdx.x;
    if (bid < 128) {                       // sub_w: (d, n-tile of 32), k = 0..127
        int d = bid >> 4, n0 = (bid & 15) * 32;
        int nn = t & 31, kk = t >> 5;      // kk 0..7
#pragma unroll
        for (int j = 0; j < 16; ++j) {
            int k = j * 8 + kk;
            float v = (k < PRE) ? sub_w[(d * PRE + k) * NEXT + n0 + nn] : 0.f;
            tile[nn][k] = f2bf(v);
        }
        __syncthreads();
        int row = t >> 3, c0 = (t & 7) * 16;
        unsigned short* dst = sub_wT + ((size_t)(d * NEXT + n0 + row)) * KP + c0;
        *reinterpret_cast<bf16x8*>(dst)     = *reinterpret_cast<bf16x8*>(&tile[row][c0]);
        *reinterpret_cast<bf16x8*>(dst + 8) = *reinterpret_cast<bf16x8*>(&tile[row][c0 + 8]);
    } else {                               // cut_w: (d, k-chunk of 128)
        int bb = bid - 128;                // 0..31
        int d = bb >> 2, k0 = (bb & 3) * 128;
        int nn = t & 31, kk = t >> 5;
#pragma unroll
        for (int j = 0; j < 16; ++j) {
            int kl = j * 8 + kk;
            tile[nn][kl] = f2bf(cut_w[(d * NEXT + k0 + kl) * SC + nn]);
        }
        __syncthreads();
        int row = t >> 3, c0 = (t & 7) * 16;
        unsigned short* dst = cut_wT + ((size_t)(d * SC + row)) * NEXT + k0 + c0;
        *reinterpret_cast<bf16x8*>(dst)     = *reinterpret_cast<bf16x8*>(&tile[row][c0]);
        *reinterpret_cast<bf16x8*>(dst + 8) = *reinterpret_cast<bf16x8*>(&tile[row][c0 + 8]);
    }
}

// ---------------------------------------------------------------------------
// k_mid: per (d, 32-row tile). Issue-early / use-late structure:
//   issue GEMM1 B-frag loads -> stage x -> barrier -> GEMM1 MFMA ->
//   issue GEMM2 B-frags + coef gathers -> h to LDS -> barrier -> LayerNorm ->
//   barrier -> GEMM2 MFMA (waves 0-3, full K, prefetched B) -> part[b][d][c].
// 512 threads = 8 waves. Grid = D*32 = 256 blocks (1/CU). No reg cap -> no spill.
// MFMA 16x16x32 bf16 layouts (m89/m91-verified):
//   A[m][k]: m = lane&15, k = (lane>>4)*8 + j   (8 contiguous bf16 = 16B)
//   B[k][n]: n = lane&15, k = (lane>>4)*8 + j
//   D[m][n]: n = lane&15, m = (lane>>4)*4 + reg
// ---------------------------------------------------------------------------
__global__ __launch_bounds__(512) void k_mid(const float* __restrict__ x,
                                             const unsigned short* __restrict__ sub_wT,
                                             const float* __restrict__ sub_b,
                                             const float* __restrict__ gamma,
                                             const float* __restrict__ beta,
                                             const unsigned short* __restrict__ cut_wT,
                                             const float* __restrict__ cut_b,
                                             const float* __restrict__ b_mat,
                                             const float* __restrict__ h_mat,
                                             const float* __restrict__ a_mat,
                                             const int* __restrict__ k_idx,
                                             float* __restrict__ part) {
    __shared__ __align__(16) unsigned short x_lds[BM][136];  // 8704 B
    __shared__ __align__(16) unsigned short h_lds[BM][536];  // 34304 B

    int t = threadIdx.x;
    int d = blockIdx.x >> 5;
    int tile = blockIdx.x & 31;
    int b0 = tile * BM;

    int w = t >> 6, lane = t & 63;
    int lr = lane >> 4, lc = lane & 15;

    // ---- issue GEMM1 B-fragment loads FIRST (latency hides under x-stage) ----
    int n0 = w * 64;
    const unsigned short* bw = sub_wT + (size_t)d * NEXT * KP + (size_t)(n0 + lc) * KP + lr * 8;
    bf16x8 bq[4][4];
#pragma unroll
    for (int ks = 0; ks < 4; ++ks)
#pragma unroll
        for (int nf = 0; nf < 4; ++nf)
            bq[ks][nf] = *reinterpret_cast<const bf16x8*>(bw + (size_t)nf * 16 * KP + ks * 32);

    // ---- stage x tile -> bf16 LDS, zero-pad rows>=B and k in [98,136) ----
    for (int idx = t; idx < BM * 136; idx += 512) {
        int r = idx / 136, i = idx - r * 136;
        int b = b0 + r;
        float v = (b < B && i < PRE) ? x[b * (D * PRE) + d * PRE + i] : 0.f;
        x_lds[r][i] = f2bf(v);
    }
    __syncthreads();

    // ---- GEMM1: (32x128) @ (128x512); wave -> 32 rows x 64 cols ----
    f32x4 acc[2][4] = {};
#pragma unroll
    for (int ks = 0; ks < 4; ++ks) {
        bf16x8 a0 = *reinterpret_cast<const bf16x8*>(&x_lds[lc][ks * 32 + lr * 8]);
        bf16x8 a1 = *reinterpret_cast<const bf16x8*>(&x_lds[16 + lc][ks * 32 + lr * 8]);
#pragma unroll
        for (int nf = 0; nf < 4; ++nf) {
            acc[0][nf] = __builtin_amdgcn_mfma_f32_16x16x32_bf16(a0, bq[ks][nf], acc[0][nf], 0, 0, 0);
            acc[1][nf] = __builtin_amdgcn_mfma_f32_16x16x32_bf16(a1, bq[ks][nf], acc[1][nf], 0, 0, 0);
        }
    }

    // ---- issue GEMM2 B-frags + coef/cut_b gathers (hide under h-write + LN) ----
    bf16x8 gq[16];
    float cf = 0.f, cb = 0.f;
    if (w < 4) {
        int nt = w & 1;
        const unsigned short* cw = cut_wT + (size_t)(d * SC + nt * 16 + lc) * NEXT + lr * 8;
#pragma unroll
        for (int ks = 0; ks < 16; ++ks)
            gq[ks] = *reinterpret_cast<const bf16x8*>(cw + ks * 32);
        int c = nt * 16 + lc;
        int kk = k_idx[c];
        float hv = 0.f;
#pragma unroll
        for (int a = 0; a < ANT; ++a)
            hv = fmaf(h_mat[(d * SC + kk) * ANT + a], a_mat[c * ANT + a], hv);
        cf = b_mat[d * SC + c] * hv;
        cb = cut_b[d * SC + c];
    }

    // ---- bias + relu -> bf16 LDS ----
    {
        const float* sb = sub_b + d * NEXT;
#pragma unroll
        for (int nf = 0; nf < 4; ++nf) {
            int n = n0 + nf * 16 + lc;
            float bias = sb[n];
#pragma unroll
            for (int mt = 0; mt < 2; ++mt)
#pragma unroll
                for (int r = 0; r < 4; ++r)
                    h_lds[mt * 16 + lr * 4 + r][n] = f2bf(fmaxf(acc[mt][nf][r] + bias, 0.f));
        }
    }
    __syncthreads();

    // ---- LayerNorm: 16 threads per row, butterfly reduce, normalize in place ----
    {
        int row = t >> 4, l16 = t & 15;
        unsigned int* hrow = reinterpret_cast<unsigned int*>(&h_lds[row][0]);
        float s1 = 0.f, s2 = 0.f;
#pragma unroll
        for (int j = 0; j < 16; ++j) {
            unsigned int p = hrow[l16 + j * 16];
            float v0 = bf2f((unsigned short)(p & 0xffffu));
            float v1 = bf2f((unsigned short)(p >> 16));
            s1 += v0 + v1;
            s2 += v0 * v0 + v1 * v1;
        }
#pragma unroll
        for (int off = 8; off >= 1; off >>= 1) {
            s1 += __shfl_xor(s1, off, 16);
            s2 += __shfl_xor(s2, off, 16);
        }
        float mu = s1 * (1.f / NEXT);
        float var = s2 * (1.f / NEXT) - mu * mu;
        float rs = rsqrtf(var + 1e-5f);
        const float* g = gamma + d * NEXT;
        const float* be = beta + d * NEXT;
#pragma unroll
        for (int j = 0; j < 16; ++j) {
            int pi = l16 + j * 16;
            unsigned int p = hrow[pi];
            int n = pi * 2;
            float v0 = (bf2f((unsigned short)(p & 0xffffu)) - mu) * rs * g[n] + be[n];
            float v1 = (bf2f((unsigned short)(p >> 16)) - mu) * rs * g[n + 1] + be[n + 1];
            hrow[pi] = (unsigned)f2bf(v0) | ((unsigned)f2bf(v1) << 16);
        }
    }
    __syncthreads();

    // ---- GEMM2: (32x512)@(512x32), waves 0-3, full K, prefetched B ----
    if (w < 4) {
        int mt = w >> 1, nt = w & 1;
        f32x4 acc2 = {};
#pragma unroll
        for (int ks = 0; ks < 16; ++ks) {
            bf16x8 a = *reinterpret_cast<const bf16x8*>(&h_lds[mt * 16 + lc][ks * 32 + lr * 8]);
            acc2 = __builtin_amdgcn_mfma_f32_16x16x32_bf16(a, gq[ks], acc2, 0, 0, 0);
        }
        int c = nt * 16 + lc;
#pragma unroll
        for (int r = 0; r < 4; ++r) {
            int m = mt * 16 + lr * 4 + r;
            int b = b0 + m;
            if (b < B) part[(b * D + d) * SC + c] = fmaxf(acc2[r] + cb, 0.f) * cf;
        }
    }
}

// ---------------------------------------------------------------------------
// k_tail: one wave per row b. 125 blocks * 8 waves = 1000 rows exactly.
// part layout [b][d][c]: each row's d-reduction input is 1 KB contiguous.
// ---------------------------------------------------------------------------
__global__ __launch_bounds__(512) void k_tail(const float* __restrict__ part,
                                              const float* __restrict__ noise,
                                              const float* __restrict__ a_mat,
                                              const float* __restrict__ clb,
                                              const float* __restrict__ fc3_w,
                                              const float* __restrict__ fc3_b,
                                              const float* __restrict__ fc4_w,
                                              const float* __restrict__ fc4_b,
                                              const float* __restrict__ out_w,
                                              const float* __restrict__ out_b,
                                              float* __restrict__ out) {
    __shared__ float w3[SC * 98];
    __shared__ float w4[98 * 49];
    __shared__ float wo[49 * 10];
    __shared__ float b3[98], b4[49], bo[10], clb_s[SC], am_s[SC * ANT];
    __shared__ float z_s[8][SC];
    __shared__ float z3_s[8][98];
    __shared__ float z4_s[8][49];

    int t = threadIdx.x;
    int w = t >> 6, lane = t & 63;
    int b = blockIdx.x * 8 + w;

    // issue the part-row load first (hides under weight staging)
    float4 v = *reinterpret_cast<const float4*>(part + (size_t)b * (D * SC) + lane * 4);

    for (int i = t; i < SC * 98; i += 512) w3[i] = fc3_w[i];
    for (int i = t; i < 98 * 49; i += 512) w4[i] = fc4_w[i];
    for (int i = t; i < 49 * 10; i += 512) wo[i] = out_w[i];
    if (t < 98) b3[t] = fc3_b[t];
    if (t < 49) b4[t] = fc4_b[t];
    if (t < 10) bo[t] = out_b[t];
    if (t >= 128 && t < 128 + SC) clb_s[t - 128] = clb[t - 128];
    if (t >= 192 && t < 192 + SC * ANT) am_s[t - 192] = a_mat[t - 192];
    __syncthreads();

    // ---- z = relu(sum_d part + noise . a_mat + clb) ----
    {
#pragma unroll
        for (int off = 8; off <= 32; off <<= 1) {
            v.x += __shfl_xor(v.x, off);
            v.y += __shfl_xor(v.y, off);
            v.z += __shfl_xor(v.z, off);
            v.w += __shfl_xor(v.w, off);
        }
        if (lane < 8) {
            int cc = lane * 4;
            float s[4] = {v.x, v.y, v.z, v.w};
#pragma unroll
            for (int i = 0; i < 4; ++i) {
                int c = cc + i;
                float zz = s[i] + clb_s[c];
#pragma unroll
                for (int a = 0; a < ANT; ++a)
                    zz = fmaf(noise[(b * SC + c) * ANT + a], am_s[c * ANT + a], zz);
                z_s[w][c] = fmaxf(zz, 0.f);
            }
        }
    }

    // fc3: 98 outputs over 64 lanes (wave-internal LDS ordering suffices)
    for (int o = lane; o < 98; o += 64) {
        float s = b3[o];
#pragma unroll
        for (int j = 0; j < SC; ++j) s = fmaf(z_s[w][j], w3[j * 98 + o], s);
        z3_s[w][o] = fmaxf(s, 0.f);
    }
    // fc4: 49 outputs
    if (lane < 49) {
        float s = b4[lane];
        for (int j = 0; j < 98; ++j) s = fmaf(z3_s[w][j], w4[j * 49 + lane], s);
        z4_s[w][lane] = fmaxf(s, 0.f);
    }
    // out: 10 logits + log_softmax (16-lane shuffle group)
    float vv = -INFINITY;
    if (lane < 10) {
        float s = bo[lane];
        for (int j = 0; j < 49; ++j) s = fmaf(z4_s[w][j], wo[j * 10 + lane], s);
        vv = s;
    }
    float mx = vv;
#pragma unroll
    for (int off = 8; off >= 1; off >>= 1) mx = fmaxf(mx, __shfl_xor(mx, off, 16));
    float e = (lane < 10) ? expf(vv - mx) : 0.f;
    float ssum = e;
#pragma unroll
    for (int off = 8; off >= 1; off >>= 1) ssum += __shfl_xor(ssum, off, 16);
    if (lane < 10) out[b * 10 + lane] = vv - mx - logf(ssum);
}

// ---------------------------------------------------------------------------
extern "C" void kernel_launch(void* const* d_in, const int* in_sizes, int n_in,
                              void* d_out, int out_size, void* d_ws, size_t ws_size,
                              hipStream_t stream) {
    const float* x      = (const float*)d_in[0];
    const float* noise  = (const float*)d_in[1];
    const float* sub_w  = (const float*)d_in[2];
    const float* sub_b  = (const float*)d_in[3];
    const float* ln_g   = (const float*)d_in[4];
    const float* ln_b   = (const float*)d_in[5];
    const float* cut_w  = (const float*)d_in[6];
    const float* cut_b  = (const float*)d_in[7];
    const float* b_mat  = (const float*)d_in[8];
    const float* h_mat  = (const float*)d_in[9];
    const float* a_mat  = (const float*)d_in[10];
    const float* clb    = (const float*)d_in[11];
    const float* fc3_w  = (const float*)d_in[12];
    const float* fc3_b  = (const float*)d_in[13];
    const float* fc4_w  = (const float*)d_in[14];
    const float* fc4_b  = (const float*)d_in[15];
    const float* out_w  = (const float*)d_in[16];
    const float* out_b  = (const float*)d_in[17];
    const int*   k_idx  = (const int*)d_in[18];
    float* out = (float*)d_out;

    char* ws = (char*)d_ws;
    float* part            = (float*)ws;                        // 1,024,000 B  [b][d][c]
    unsigned short* sub_wT = (unsigned short*)(ws + (1 << 20)); // 1,048,576 B
    unsigned short* cut_wT = (unsigned short*)(ws + (2 << 20)); // 262,144 B

    k_prep<<<160, 256, 0, stream>>>(sub_w, cut_w, sub_wT, cut_wT);
    k_mid<<<D * NTILE, 512, 0, stream>>>(x, sub_wT, sub_b, ln_g, ln_b, cut_wT,
                                         cut_b, b_mat, h_mat, a_mat, k_idx, part);
    k_tail<<<125, 512, 0, stream>>>(part, noise, a_mat, clb, fc3_w, fc3_b,
                                    fc4_w, fc4_b, out_w, out_b, out);
}

// Round 9
// 28.896 us; speedup vs baseline: 1.0838x; 1.0838x over previous
//
#include <hip/hip_runtime.h>
#include <math.h>

#define B 1000
#define D 8
#define PRE 98
#define NEXT 512
#define SC 32
#define ANT 5
#define BM 32
#define NTILE 32          // 1000/32 -> 32 tiles (last partial)
#define KP 128            // PRE padded to 128 for MFMA K-steps
#define CSTRIDE 32        // counter padding: 1 counter per 128-B line

// tail-weight LDS layout (floats)
#define OW3 0
#define OW4 3136
#define OWO 7938
#define OB3 8428
#define OB4 8526
#define OBO 8575
#define WTOT 8585

using bf16x8 = __attribute__((ext_vector_type(8))) short;
using f32x4  = __attribute__((ext_vector_type(4))) float;

static __device__ __forceinline__ unsigned short f2bf(float f) {
    union { float f; unsigned u; } v{f};
    unsigned r = (v.u + 0x7fffu + ((v.u >> 16) & 1u)) >> 16;
    return (unsigned short)r;
}
static __device__ __forceinline__ float bf2f(unsigned short h) {
    union { unsigned u; float f; } v{(unsigned)h << 16};
    return v.f;
}

// ---------------------------------------------------------------------------
// Prep: zero (padded) tile counters with agent-coherent stores + transpose
// weights to bf16: sub_wT[d][n][k] = sub_w[d][k][n] (k zero-padded to 128),
//                  cut_wT[d][c][k] = cut_w[d][k][c]
// ---------------------------------------------------------------------------
__global__ __launch_bounds__(256) void k_prep(const float* __restrict__ sub_w,
                                              const float* __restrict__ cut_w,
                                              unsigned short* __restrict__ sub_wT,
                                              unsigned short* __restrict__ cut_wT,
                                              int* __restrict__ counters) {
    __shared__ __align__(16) unsigned short tile[32][128];
    int t = threadIdx.x, bid = blockIdx.x;
    if (bid == 0 && t < NTILE)
        __hip_atomic_store(&counters[t * CSTRIDE], 0, __ATOMIC_RELAXED,
                           __HIP_MEMORY_SCOPE_AGENT);
    if (bid < 128) {                       // sub_w: (d, n-tile of 32), k = 0..127
        int d = bid >> 4, n0 = (bid & 15) * 32;
        int nn = t & 31, kk = t >> 5;      // kk 0..7
#pragma unroll
        for (int j = 0; j < 16; ++j) {
            int k = j * 8 + kk;
            float v = (k < PRE) ? sub_w[(d * PRE + k) * NEXT + n0 + nn] : 0.f;
            tile[nn][k] = f2bf(v);
        }
        __syncthreads();
        int row = t >> 3, c0 = (t & 7) * 16;
        unsigned short* dst = sub_wT + ((size_t)(d * NEXT + n0 + row)) * KP + c0;
        *reinterpret_cast<bf16x8*>(dst)     = *reinterpret_cast<bf16x8*>(&tile[row][c0]);
        *reinterpret_cast<bf16x8*>(dst + 8) = *reinterpret_cast<bf16x8*>(&tile[row][c0 + 8]);
    } else {                               // cut_w: (d, k-chunk of 128)
        int bb = bid - 128;                // 0..31
        int d = bb >> 2, k0 = (bb & 3) * 128;
        int nn = t & 31, kk = t >> 5;
#pragma unroll
        for (int j = 0; j < 16; ++j) {
            int kl = j * 8 + kk;
            tile[nn][kl] = f2bf(cut_w[(d * NEXT + k0 + kl) * SC + nn]);
        }
        __syncthreads();
        int row = t >> 3, c0 = (t & 7) * 16;
        unsigned short* dst = cut_wT + ((size_t)(d * SC + row)) * NEXT + k0 + c0;
        *reinterpret_cast<bf16x8*>(dst)     = *reinterpret_cast<bf16x8*>(&tile[row][c0]);
        *reinterpret_cast<bf16x8*>(dst + 8) = *reinterpret_cast<bf16x8*>(&tile[row][c0 + 8]);
    }
}

// ---------------------------------------------------------------------------
// k_all: per (d, 32-row tile): GEMM1 (MFMA, issue-early B) -> bias/relu ->
//   LayerNorm -> GEMM2 (waves 0-3, coherent part stores) || tail-weight stage
//   (waves 4-7) -> per-tile counter + spin (fence-free, padded line) ->
//   each block runs the tail MLP for its own 4 rows.
// 512 threads = 8 waves. Grid = D*32 = 256 blocks (1/CU, all co-resident).
// Cross-block data moves ONLY via relaxed AGENT-scope atomic load/store
// (sc0/sc1 coherent accesses, no L2-flush fences).
// MFMA 16x16x32 bf16 layouts (m89/m91-verified):
//   A[m][k]: m = lane&15, k = (lane>>4)*8 + j   (8 contiguous bf16 = 16B)
//   B[k][n]: n = lane&15, k = (lane>>4)*8 + j
//   D[m][n]: n = lane&15, m = (lane>>4)*4 + reg
// ---------------------------------------------------------------------------
__global__ __launch_bounds__(512) void k_all(const float* __restrict__ x,
                                             const unsigned short* __restrict__ sub_wT,
                                             const float* __restrict__ sub_b,
                                             const float* __restrict__ gamma,
                                             const float* __restrict__ beta,
                                             const unsigned short* __restrict__ cut_wT,
                                             const float* __restrict__ cut_b,
                                             const float* __restrict__ b_mat,
                                             const float* __restrict__ h_mat,
                                             const float* __restrict__ a_mat,
                                             const int* __restrict__ k_idx,
                                             const float* __restrict__ noise,
                                             const float* __restrict__ clb,
                                             const float* __restrict__ fc3_w,
                                             const float* __restrict__ fc3_b,
                                             const float* __restrict__ fc4_w,
                                             const float* __restrict__ fc4_b,
                                             const float* __restrict__ out_w,
                                             const float* __restrict__ out_b,
                                             float* __restrict__ part,
                                             int* __restrict__ counters,
                                             float* __restrict__ out) {
    __shared__ __align__(16) unsigned short x_lds[BM][136];  //  8704 B
    __shared__ __align__(16) unsigned short h_lds[BM][536];  // 34304 B
    __shared__ float W_lds[WTOT];                            // 34340 B
    __shared__ float clb_s[SC], am_s[SC * ANT];
    __shared__ float z_s[4][SC];
    __shared__ float z3_s[4][98];
    __shared__ float z4_s[4][49];

    int t = threadIdx.x;
    int d = blockIdx.x >> 5;
    int tile = blockIdx.x & 31;
    int b0 = tile * BM;
    int w = t >> 6, lane = t & 63;
    int lr = lane >> 4, lc = lane & 15;

    // ---- issue GEMM1 B-fragment loads FIRST (latency hides under x-stage) ----
    int n0 = w * 64;
    const unsigned short* bw = sub_wT + (size_t)d * NEXT * KP + (size_t)(n0 + lc) * KP + lr * 8;
    bf16x8 bq[4][4];
#pragma unroll
    for (int ks = 0; ks < 4; ++ks)
#pragma unroll
        for (int nf = 0; nf < 4; ++nf)
            bq[ks][nf] = *reinterpret_cast<const bf16x8*>(bw + (size_t)nf * 16 * KP + ks * 32);

    // ---- stage x tile -> bf16 LDS, zero-pad rows>=B and k in [98,136) ----
    for (int idx = t; idx < BM * 136; idx += 512) {
        int r = idx / 136, i = idx - r * 136;
        int b = b0 + r;
        float v = (b < B && i < PRE) ? x[b * (D * PRE) + d * PRE + i] : 0.f;
        x_lds[r][i] = f2bf(v);
    }
    __syncthreads();

    // ---- GEMM1: (32x128) @ (128x512); wave -> 32 rows x 64 cols ----
    f32x4 acc[2][4] = {};
#pragma unroll
    for (int ks = 0; ks < 4; ++ks) {
        bf16x8 a0 = *reinterpret_cast<const bf16x8*>(&x_lds[lc][ks * 32 + lr * 8]);
        bf16x8 a1 = *reinterpret_cast<const bf16x8*>(&x_lds[16 + lc][ks * 32 + lr * 8]);
#pragma unroll
        for (int nf = 0; nf < 4; ++nf) {
            acc[0][nf] = __builtin_amdgcn_mfma_f32_16x16x32_bf16(a0, bq[ks][nf], acc[0][nf], 0, 0, 0);
            acc[1][nf] = __builtin_amdgcn_mfma_f32_16x16x32_bf16(a1, bq[ks][nf], acc[1][nf], 0, 0, 0);
        }
    }

    // ---- issue GEMM2 B-frags + coef/cut_b gathers (hide under h-write + LN) ----
    bf16x8 gq[16];
    float cf = 0.f, cb = 0.f;
    if (w < 4) {
        int nt = w & 1;
        const unsigned short* cw = cut_wT + (size_t)(d * SC + nt * 16 + lc) * NEXT + lr * 8;
#pragma unroll
        for (int ks = 0; ks < 16; ++ks)
            gq[ks] = *reinterpret_cast<const bf16x8*>(cw + ks * 32);
        int c = nt * 16 + lc;
        int kk = k_idx[c];
        float hv = 0.f;
#pragma unroll
        for (int a = 0; a < ANT; ++a)
            hv = fmaf(h_mat[(d * SC + kk) * ANT + a], a_mat[c * ANT + a], hv);
        cf = b_mat[d * SC + c] * hv;
        cb = cut_b[d * SC + c];
    }

    // ---- bias + relu -> bf16 LDS ----
    {
        const float* sb = sub_b + d * NEXT;
#pragma unroll
        for (int nf = 0; nf < 4; ++nf) {
            int n = n0 + nf * 16 + lc;
            float bias = sb[n];
#pragma unroll
            for (int mt = 0; mt < 2; ++mt)
#pragma unroll
                for (int r = 0; r < 4; ++r)
                    h_lds[mt * 16 + lr * 4 + r][n] = f2bf(fmaxf(acc[mt][nf][r] + bias, 0.f));
        }
    }
    __syncthreads();

    // ---- LayerNorm: 16 threads per row, butterfly reduce, normalize in place ----
    {
        int row = t >> 4, l16 = t & 15;
        unsigned int* hrow = reinterpret_cast<unsigned int*>(&h_lds[row][0]);
        float s1 = 0.f, s2 = 0.f;
#pragma unroll
        for (int j = 0; j < 16; ++j) {
            unsigned int p = hrow[l16 + j * 16];
            float v0 = bf2f((unsigned short)(p & 0xffffu));
            float v1 = bf2f((unsigned short)(p >> 16));
            s1 += v0 + v1;
            s2 += v0 * v0 + v1 * v1;
        }
#pragma unroll
        for (int off = 8; off >= 1; off >>= 1) {
            s1 += __shfl_xor(s1, off, 16);
            s2 += __shfl_xor(s2, off, 16);
        }
        float mu = s1 * (1.f / NEXT);
        float var = s2 * (1.f / NEXT) - mu * mu;
        float rs = rsqrtf(var + 1e-5f);
        const float* g = gamma + d * NEXT;
        const float* be = beta + d * NEXT;
#pragma unroll
        for (int j = 0; j < 16; ++j) {
            int pi = l16 + j * 16;
            unsigned int p = hrow[pi];
            int n = pi * 2;
            float v0 = (bf2f((unsigned short)(p & 0xffffu)) - mu) * rs * g[n] + be[n];
            float v1 = (bf2f((unsigned short)(p >> 16)) - mu) * rs * g[n + 1] + be[n + 1];
            hrow[pi] = (unsigned)f2bf(v0) | ((unsigned)f2bf(v1) << 16);
        }
    }
    __syncthreads();

    // ---- GEMM2 (waves 0-3) with coherent part stores || tail stage (waves 4-7) ----
    if (w < 4) {
        int mt = w >> 1, nt = w & 1;
        f32x4 acc2 = {};
#pragma unroll
        for (int ks = 0; ks < 16; ++ks) {
            bf16x8 a = *reinterpret_cast<const bf16x8*>(&h_lds[mt * 16 + lc][ks * 32 + lr * 8]);
            acc2 = __builtin_amdgcn_mfma_f32_16x16x32_bf16(a, gq[ks], acc2, 0, 0, 0);
        }
        int c = nt * 16 + lc;
#pragma unroll
        for (int r = 0; r < 4; ++r) {
            int m = mt * 16 + lr * 4 + r;
            int b = b0 + m;
            if (b < B)
                __hip_atomic_store(&part[((size_t)b * D + d) * SC + c],
                                   fmaxf(acc2[r] + cb, 0.f) * cf,
                                   __ATOMIC_RELAXED, __HIP_MEMORY_SCOPE_AGENT);
        }
    } else {
        int tt = t - 256;  // 0..255
        for (int i = tt; i < 3136; i += 256) W_lds[OW3 + i] = fc3_w[i];
        for (int i = tt; i < 4802; i += 256) W_lds[OW4 + i] = fc4_w[i];
        for (int i = tt; i < 490; i += 256)  W_lds[OWO + i] = out_w[i];
        if (tt < 98) W_lds[OB3 + tt] = fc3_b[tt];
        if (tt < 49) W_lds[OB4 + tt] = fc4_b[tt];
        if (tt < 10) W_lds[OBO + tt] = out_b[tt];
        if (tt >= 128 && tt < 128 + SC) clb_s[tt - 128] = clb[tt - 128];
        if (tt >= 160 && tt < 160 + SC * ANT) am_s[tt - 160] = a_mat[tt - 160];
    }

    // ---- per-tile sync: coherent stores are drained by the vmcnt(0) that
    // __syncthreads emits; relaxed RMW + spin on a padded private line.
    __syncthreads();
    if (t == 0) {
        __hip_atomic_fetch_add(&counters[tile * CSTRIDE], 1,
                               __ATOMIC_RELAXED, __HIP_MEMORY_SCOPE_AGENT);
        while (__hip_atomic_load(&counters[tile * CSTRIDE],
                                 __ATOMIC_RELAXED, __HIP_MEMORY_SCOPE_AGENT) < D)
            __builtin_amdgcn_s_sleep(2);
    }
    __syncthreads();

    // ---- tail MLP: this block handles rows d*4 .. d*4+3; wave w<4 -> one row ----
    if (w < 4) {
        int b = b0 + d * 4 + w;
        if (b < B) {
            // z = relu(sum_d part + noise . a_mat + clb); coherent part loads
            int c = lane & 31, dg = lane >> 5;   // dg in {0,1}
            float s = 0.f;
#pragma unroll
            for (int i = 0; i < 4; ++i)
                s += __hip_atomic_load(&part[((size_t)b * D + (dg + 2 * i)) * SC + c],
                                       __ATOMIC_RELAXED, __HIP_MEMORY_SCOPE_AGENT);
            s += __shfl_xor(s, 32);
            if (lane < 32) {
                float zz = s + clb_s[c];
#pragma unroll
                for (int a = 0; a < ANT; ++a)
                    zz = fmaf(noise[(b * SC + c) * ANT + a], am_s[c * ANT + a], zz);
                z_s[w][c] = fmaxf(zz, 0.f);
            }
            // fc3: 98 outputs over 64 lanes
            for (int o = lane; o < 98; o += 64) {
                float s3 = W_lds[OB3 + o];
#pragma unroll
                for (int j = 0; j < SC; ++j) s3 = fmaf(z_s[w][j], W_lds[OW3 + j * 98 + o], s3);
                z3_s[w][o] = fmaxf(s3, 0.f);
            }
            // fc4: 49 outputs
            if (lane < 49) {
                float s4 = W_lds[OB4 + lane];
                for (int j = 0; j < 98; ++j) s4 = fmaf(z3_s[w][j], W_lds[OW4 + j * 49 + lane], s4);
                z4_s[w][lane] = fmaxf(s4, 0.f);
            }
            // out: 10 logits + log_softmax (16-lane shuffle group)
            float v = -INFINITY;
            if (lane < 10) {
                float so = W_lds[OBO + lane];
                for (int j = 0; j < 49; ++j) so = fmaf(z4_s[w][j], W_lds[OWO + j * 10 + lane], so);
                v = so;
            }
            float mx = v;
#pragma unroll
            for (int off = 8; off >= 1; off >>= 1) mx = fmaxf(mx, __shfl_xor(mx, off, 16));
            float e = (lane < 10) ? expf(v - mx) : 0.f;
            float ssum = e;
#pragma unroll
            for (int off = 8; off >= 1; off >>= 1) ssum += __shfl_xor(ssum, off, 16);
            if (lane < 10) out[b * 10 + lane] = v - mx - logf(ssum);
        }
    }
}

// ---------------------------------------------------------------------------
extern "C" void kernel_launch(void* const* d_in, const int* in_sizes, int n_in,
                              void* d_out, int out_size, void* d_ws, size_t ws_size,
                              hipStream_t stream) {
    const float* x      = (const float*)d_in[0];
    const float* noise  = (const float*)d_in[1];
    const float* sub_w  = (const float*)d_in[2];
    const float* sub_b  = (const float*)d_in[3];
    const float* ln_g   = (const float*)d_in[4];
    const float* ln_b   = (const float*)d_in[5];
    const float* cut_w  = (const float*)d_in[6];
    const float* cut_b  = (const float*)d_in[7];
    const float* b_mat  = (const float*)d_in[8];
    const float* h_mat  = (const float*)d_in[9];
    const float* a_mat  = (const float*)d_in[10];
    const float* clb    = (const float*)d_in[11];
    const float* fc3_w  = (const float*)d_in[12];
    const float* fc3_b  = (const float*)d_in[13];
    const float* fc4_w  = (const float*)d_in[14];
    const float* fc4_b  = (const float*)d_in[15];
    const float* out_w  = (const float*)d_in[16];
    const float* out_b  = (const float*)d_in[17];
    const int*   k_idx  = (const int*)d_in[18];
    float* out = (float*)d_out;

    char* ws = (char*)d_ws;
    float* part            = (float*)ws;                        // 1,024,000 B  [b][d][c]
    unsigned short* sub_wT = (unsigned short*)(ws + (1 << 20)); // 1,048,576 B
    unsigned short* cut_wT = (unsigned short*)(ws + (2 << 20)); // 262,144 B
    int* counters          = (int*)(ws + (2 << 20) + (1 << 18)); // 4 KB (padded)

    k_prep<<<160, 256, 0, stream>>>(sub_w, cut_w, sub_wT, cut_wT, counters);
    k_all<<<D * NTILE, 512, 0, stream>>>(x, sub_wT, sub_b, ln_g, ln_b, cut_wT,
                                         cut_b, b_mat, h_mat, a_mat, k_idx,
                                         noise, clb, fc3_w, fc3_b, fc4_w,
                                         fc4_b, out_w, out_b, part, counters,
                                         out);
}